// Round 4
// baseline (4733.503 us; speedup 1.0000x reference)
//
#include <hip/hip_runtime.h>

// Problem constants
#define BTOT 1024
#define TPTS 96
#define NV   7
#define HD   64
#define NH   256   // ode hidden (4*H)

// LDS layout (float offsets), total 39776 floats = 159104 B (1 block/CU)
#define OFF_W1T   0        // [256 cols][64 K] transposed + XOR-swizzled = 16384
#define OFF_W2T   16384    // [64 cols][256 K] transposed + XOR-swizzled = 16384
#define OFF_YS    32768    // [4 el][3][64] state broadcast               = 768
#define OFF_TS    33536    // [16 wave][3][64] tanh broadcast             = 3072
#define OFF_PARTS 36608    // [4 el][4 q][3][64] L2 partials              = 3072
#define OFF_TPS   39680    // 96
#define SMEM_FLOATS 39776
#define SMEM_BYTES  (SMEM_FLOATS * 4)

__device__ __forceinline__ float rdlane(float v, int i) {
    return __int_as_float(__builtin_amdgcn_readlane(__float_as_int(v), i));
}
__device__ __forceinline__ float wsum64(float v) {
    v += __shfl_xor(v, 1);  v += __shfl_xor(v, 2);  v += __shfl_xor(v, 4);
    v += __shfl_xor(v, 8);  v += __shfl_xor(v, 16); v += __shfl_xor(v, 32);
    return v;
}
__device__ __forceinline__ float tanh_fast(float x) {
    float e = __expf(2.f * x);
    return 1.f - 2.f / (e + 1.f);
}

// 4 waves per batch element; block = 1024 thr = 16 waves = 4 elements; grid = 256 (1 block/CU).
// State in regs (redundant across the element's waves); y/t broadcast via uniform ds_read_b128;
// weights transposed + swizzled in LDS for per-lane ds_read_b128.
__global__ __launch_bounds__(1024, 4)
void node_fused4(const float* __restrict__ x,
                 const float* __restrict__ iw1, const float* __restrict__ ib1,
                 const float* __restrict__ iw2, const float* __restrict__ ib2,
                 const float* __restrict__ ow1, const float* __restrict__ ob1,
                 const float* __restrict__ ow2, const float* __restrict__ ob2,
                 const float* __restrict__ inter, const float* __restrict__ cons,
                 const float* __restrict__ dw1, const float* __restrict__ db1,
                 const float* __restrict__ dw2, const float* __restrict__ db2,
                 const float* __restrict__ tpts,
                 float* __restrict__ out)
{
    extern __shared__ float sm[];
    float* W1s = sm + OFF_W1T;   // [c][i'] c<256, i swizzled
    float* W2s = sm + OFF_W2T;   // [o][k'] o<64, k swizzled
    float* YSs = sm + OFF_YS;    // [el][r][64]
    float* TSs = sm + OFF_TS;    // [wave][r][64]
    float* PRT = sm + OFF_PARTS; // [el][q][r][64]
    float* tps = sm + OFF_TPS;

    const int tid = threadIdx.x;
    const int w   = tid >> 6;        // wave 0..15
    const int ln  = tid & 63;
    const int el  = w >> 2;          // element within block 0..3
    const int q   = w & 3;           // K-chunk / hidden-col group
    const int b   = blockIdx.x * 4 + el;
    const int c   = q * 64 + ln;     // my hidden column in [0,256)
    const int swz = ln & 7;          // granule XOR swizzle (c&7 == ln&7)

    // ---- stage W1^T swizzled: logical W1T[c][i] at phys c*64 + ((i/4)^(c&7))*4 + i%4 ----
    for (int idx = tid; idx < HD * NH; idx += 1024) {
        int i = idx >> 8, cc = idx & 255;          // ow1[i][cc]
        int g = i >> 2, of = i & 3;
        W1s[cc * 64 + ((g ^ (cc & 7)) << 2) + of] = ow1[idx];
    }
    // ---- stage W2^T swizzled: logical W2T[o][k] at phys o*256 + ((k/4)^(o&7))*4 + k%4 ----
    for (int idx = tid; idx < NH * HD; idx += 1024) {
        int k = idx >> 6, o = idx & 63;            // ow2[k][o]
        int g = k >> 2, of = k & 3;
        W2s[o * 256 + ((g ^ (o & 7)) << 2) + of] = ow2[idx];
    }
    if (tid < TPTS) tps[tid] = tpts[tid];

    // ---- per-thread constants ----
    const float w64c = ow1[64 * NH + c];   // ie feature weight
    const float w65c = ow1[65 * NH + c];   // t feature weight
    const float b1c  = ob1[c];
    const float b2c  = ob2[ln];
    float db1c = 0.f, dvv0=0,dvv1=0,dvv2=0,dvv3=0,dvv4=0,dvv5=0,dvv6=0;
    float dbv0=0,dbv1=0,dbv2=0,dbv3=0,dbv4=0,dbv5=0,dbv6=0;
    if (q < 3) {
        db1c = db1[q * HD + ln];
        const float* dvp = dw2 + ((size_t)q * HD + ln) * NV;
        dvv0=dvp[0]; dvv1=dvp[1]; dvv2=dvp[2]; dvv3=dvp[3]; dvv4=dvp[4]; dvv5=dvp[5]; dvv6=dvp[6];
        const float* dbp = db2 + q * NV;
        dbv0=dbp[0]; dbv1=dbp[1]; dbv2=dbp[2]; dbv3=dbp[3]; dbv4=dbp[4]; dbv5=dbp[5]; dbv6=dbp[6];
    }

    // M = conservation @ interaction (3x3)
    float M00,M01,M02,M10,M11,M12,M20,M21,M22;
    {
        float I0=inter[0],I1=inter[1],I2=inter[2],I3=inter[3],I4=inter[4];
        float I5=inter[5],I6=inter[6],I7=inter[7],I8=inter[8];
        float C0=cons[0],C1=cons[1],C2=cons[2],C3=cons[3],C4=cons[4];
        float C5=cons[5],C6=cons[6],C7=cons[7],C8=cons[8];
        M00=C0*I0+C1*I3+C2*I6; M01=C0*I1+C1*I4+C2*I7; M02=C0*I2+C1*I5+C2*I8;
        M10=C3*I0+C4*I3+C5*I6; M11=C3*I1+C4*I4+C5*I7; M12=C3*I2+C4*I5+C5*I8;
        M20=C6*I0+C7*I3+C8*I6; M21=C6*I1+C7*I4+C8*I7; M22=C6*I2+C7*I5+C8*I8;
    }

    // ---- initial state (redundant across the element's 4 waves; bitwise identical) ----
    float xs0,xs1,xs2,xs3,xs4,xs5,xs6;
    {
        const float* xp = x + (size_t)b * TPTS * NV + ln * NV;     // t = ln
        float v0=xp[0],v1=xp[1],v2=xp[2],v3=xp[3],v4=xp[4],v5=xp[5],v6=xp[6];
        if (ln < 32) {                                             // t = 64 + ln
            const float* xp2 = xp + 64 * NV;
            v0+=xp2[0]; v1+=xp2[1]; v2+=xp2[2]; v3+=xp2[3]; v4+=xp2[4]; v5+=xp2[5]; v6+=xp2[6];
        }
        xs0=wsum64(v0)*(1.f/96.f); xs1=wsum64(v1)*(1.f/96.f); xs2=wsum64(v2)*(1.f/96.f);
        xs3=wsum64(v3)*(1.f/96.f); xs4=wsum64(v4)*(1.f/96.f); xs5=wsum64(v5)*(1.f/96.f);
        xs6=wsum64(v6)*(1.f/96.f);
    }
    float h0v;
    {
        float a = ib1[ln];
        a = fmaf(xs0, iw1[0*HD+ln], a); a = fmaf(xs1, iw1[1*HD+ln], a);
        a = fmaf(xs2, iw1[2*HD+ln], a); a = fmaf(xs3, iw1[3*HD+ln], a);
        a = fmaf(xs4, iw1[4*HD+ln], a); a = fmaf(xs5, iw1[5*HD+ln], a);
        a = fmaf(xs6, iw1[6*HD+ln], a);
        h0v = fmaxf(a, 0.f);
    }
    float yb0, yb1, yb2;
    {
        float a0 = ib2[ln], a1 = ib2[64 + ln], a2 = ib2[128 + ln];
        #pragma unroll
        for (int k = 0; k < 64; ++k) {
            float hk = rdlane(h0v, k);
            a0 = fmaf(hk, iw2[k * 192 + ln], a0);
            a1 = fmaf(hk, iw2[k * 192 + 64 + ln], a1);
            a2 = fmaf(hk, iw2[k * 192 + 128 + ln], a2);
        }
        yb0 = a0; yb1 = a1; yb2 = a2;
    }
    // publish committed state for decode(0) (all 4 waves write identical data)
    {
        float* yp = YSs + el * 192 + ln;
        yp[0] = yb0; yp[64] = yb1; yp[128] = yb2;
    }
    __syncthreads();   // weights + YS ready

    // ---- one ODE-func eval; 2 barriers (single-buffered partial exchange) ----
    auto eval_f = [&](float ts, float ys0, float ys1, float ys2,
                      float& d0, float& d1, float& d2) {
        // component means -> interaction effects (identical across the element's waves)
        float s0 = wsum64(ys0) * (1.f / 64.f);
        float s1 = wsum64(ys1) * (1.f / 64.f);
        float s2 = wsum64(ys2) * (1.f / 64.f);
        float e0 = fmaf(M02, s2, fmaf(M01, s1, M00 * s0));
        float e1 = fmaf(M12, s2, fmaf(M11, s1, M10 * s0));
        float e2 = fmaf(M22, s2, fmaf(M21, s1, M20 * s0));
        // publish ys (all 4 waves, identical bits -> benign race; own-wave RAW is ordered)
        {
            float* yp = YSs + el * 192 + ln;
            yp[0] = ys0; yp[64] = ys1; yp[128] = ys2;
        }
        // layer 1: a_r = b1 + w64*e_r + w65*ts + sum_i y_r[i]*W1[i][c]
        float a0 = fmaf(w64c, e0, fmaf(w65c, ts, b1c));
        float a1 = fmaf(w64c, e1, fmaf(w65c, ts, b1c));
        float a2 = fmaf(w64c, e2, fmaf(w65c, ts, b1c));
        {
            const float4* wp = (const float4*)(W1s + c * 64);
            const float4* yp = (const float4*)(YSs + el * 192);
            #pragma unroll
            for (int g = 0; g < 16; ++g) {
                float4 wv = wp[g ^ swz];                 // swizzled, conflict-free
                float4 y0 = yp[g], y1 = yp[16 + g], y2 = yp[32 + g];  // uniform broadcast
                a0 = fmaf(y0.w,wv.w, fmaf(y0.z,wv.z, fmaf(y0.y,wv.y, fmaf(y0.x,wv.x, a0))));
                a1 = fmaf(y1.w,wv.w, fmaf(y1.z,wv.z, fmaf(y1.y,wv.y, fmaf(y1.x,wv.x, a1))));
                a2 = fmaf(y2.w,wv.w, fmaf(y2.z,wv.z, fmaf(y2.y,wv.y, fmaf(y2.x,wv.x, a2))));
            }
        }
        float t0 = tanh_fast(a0), t1 = tanh_fast(a1), t2 = tanh_fast(a2);
        // publish tanh slice (wave-private region; no cross-wave hazard)
        {
            float* tp = TSs + w * 192 + ln;
            tp[0] = t0; tp[64] = t1; tp[128] = t2;
        }
        // layer 2 partial: out col ln, K over my 64-chunk
        float p0 = 0.f, p1 = 0.f, p2 = 0.f;
        {
            const float4* wp = (const float4*)(W2s + ln * 256);
            const float4* tp = (const float4*)(TSs + w * 192);
            #pragma unroll
            for (int g = 0; g < 16; ++g) {
                float4 wv = wp[16 * q + (g ^ swz)];      // swizzled, conflict-free
                float4 u0 = tp[g], u1 = tp[16 + g], u2 = tp[32 + g];  // uniform broadcast
                p0 = fmaf(u0.w,wv.w, fmaf(u0.z,wv.z, fmaf(u0.y,wv.y, fmaf(u0.x,wv.x, p0))));
                p1 = fmaf(u1.w,wv.w, fmaf(u1.z,wv.z, fmaf(u1.y,wv.y, fmaf(u1.x,wv.x, p1))));
                p2 = fmaf(u2.w,wv.w, fmaf(u2.z,wv.z, fmaf(u2.y,wv.y, fmaf(u2.x,wv.x, p2))));
            }
        }
        // exchange partials across the element's 4 waves (single buffer, 2 barriers)
        {
            float* mp = PRT + (el * 4 + q) * 192 + ln;
            mp[0] = p0; mp[64] = p1; mp[128] = p2;
        }
        __syncthreads();
        const float* rp = PRT + el * 768 + ln;
        d0 = b2c + ((rp[0]   + rp[192])     + (rp[384]     + rp[576]));
        d1 = b2c + ((rp[64]  + rp[192+64])  + (rp[384+64]  + rp[576+64]));
        d2 = b2c + ((rp[128] + rp[192+128]) + (rp[384+128] + rp[576+128]));
        __syncthreads();   // protect PRT from next eval's writes
    };

    // ---- fused decode of committed state (in YSs) at time index tix ----
    auto decode = [&](int tix) {
        if (q < 3) {
            float acc = db1c;
            const float4* yp = (const float4*)(YSs + el * 192 + q * 64);
            const float*  wp = dw1 + (size_t)q * HD * HD + ln;
            #pragma unroll
            for (int g = 0; g < 16; ++g) {
                float4 yv = yp[g];                       // uniform broadcast
                acc = fmaf(yv.x, wp[(4*g  ) * 64], acc);
                acc = fmaf(yv.y, wp[(4*g+1) * 64], acc);
                acc = fmaf(yv.z, wp[(4*g+2) * 64], acc);
                acc = fmaf(yv.w, wp[(4*g+3) * 64], acc);
            }
            float hid = fmaxf(acc, 0.f);
            float pv;
            pv = wsum64(hid * dvv0); if (ln==0) out[(((size_t)q*BTOT+b)*TPTS+tix)*NV+0] = pv + dbv0;
            pv = wsum64(hid * dvv1); if (ln==0) out[(((size_t)q*BTOT+b)*TPTS+tix)*NV+1] = pv + dbv1;
            pv = wsum64(hid * dvv2); if (ln==0) out[(((size_t)q*BTOT+b)*TPTS+tix)*NV+2] = pv + dbv2;
            pv = wsum64(hid * dvv3); if (ln==0) out[(((size_t)q*BTOT+b)*TPTS+tix)*NV+3] = pv + dbv3;
            pv = wsum64(hid * dvv4); if (ln==0) out[(((size_t)q*BTOT+b)*TPTS+tix)*NV+4] = pv + dbv4;
            pv = wsum64(hid * dvv5); if (ln==0) out[(((size_t)q*BTOT+b)*TPTS+tix)*NV+5] = pv + dbv5;
            pv = wsum64(hid * dvv6); if (ln==0) out[(((size_t)q*BTOT+b)*TPTS+tix)*NV+6] = pv + dbv6;
        }
    };

    // ---- RK4 over 95 intervals ----
    decode(0);
    float d0, d1, d2;
    #pragma unroll 1
    for (int s = 0; s < TPTS - 1; ++s) {
        const float ta = tps[s], tb = tps[s + 1];
        const float dt = tb - ta, hdt = 0.5f * dt;

        eval_f(ta, yb0, yb1, yb2, d0, d1, d2);
        float k0 = d0, k1 = d1, k2 = d2;

        eval_f(ta + hdt, fmaf(hdt, d0, yb0), fmaf(hdt, d1, yb1), fmaf(hdt, d2, yb2),
               d0, d1, d2);
        k0 += 2.f * d0; k1 += 2.f * d1; k2 += 2.f * d2;

        eval_f(ta + hdt, fmaf(hdt, d0, yb0), fmaf(hdt, d1, yb1), fmaf(hdt, d2, yb2),
               d0, d1, d2);
        k0 += 2.f * d0; k1 += 2.f * d1; k2 += 2.f * d2;

        eval_f(tb, fmaf(dt, d0, yb0), fmaf(dt, d1, yb1), fmaf(dt, d2, yb2),
               d0, d1, d2);
        k0 += d0; k1 += d1; k2 += d2;

        const float c6 = dt * (1.f / 6.f);
        yb0 = fmaf(c6, k0, yb0); yb1 = fmaf(c6, k1, yb1); yb2 = fmaf(c6, k2, yb2);

        // publish committed state for decode (identical bits from all 4 waves)
        {
            float* yp = YSs + el * 192 + ln;
            yp[0] = yb0; yp[64] = yb1; yp[128] = yb2;
        }
        decode(s + 1);
    }
}

extern "C" void kernel_launch(void* const* d_in, const int* in_sizes, int n_in,
                              void* d_out, int out_size, void* d_ws, size_t ws_size,
                              hipStream_t stream) {
    const float* x     = (const float*)d_in[0];
    const float* iw1   = (const float*)d_in[1];
    const float* ib1   = (const float*)d_in[2];
    const float* iw2   = (const float*)d_in[3];
    const float* ib2   = (const float*)d_in[4];
    const float* ow1   = (const float*)d_in[5];
    const float* ob1   = (const float*)d_in[6];
    const float* ow2   = (const float*)d_in[7];
    const float* ob2   = (const float*)d_in[8];
    const float* inter = (const float*)d_in[9];
    const float* cons  = (const float*)d_in[10];
    const float* dw1   = (const float*)d_in[11];
    const float* db1   = (const float*)d_in[12];
    const float* dw2   = (const float*)d_in[13];
    const float* db2   = (const float*)d_in[14];
    const float* tpts  = (const float*)d_in[15];
    float* out = (float*)d_out;

    (void)hipFuncSetAttribute((const void*)node_fused4,
                              hipFuncAttributeMaxDynamicSharedMemorySize,
                              SMEM_BYTES);

    node_fused4<<<BTOT / 4, 1024, SMEM_BYTES, stream>>>(
        x, iw1, ib1, iw2, ib2, ow1, ob1, ow2, ob2,
        inter, cons, dw1, db1, dw2, db2, tpts, out);
}

// Round 5
// 2175.350 us; speedup vs baseline: 2.1760x; 2.1760x over previous
//
#include <hip/hip_runtime.h>

// Problem constants
#define BTOT 1024
#define TPTS 96
#define NV   7
#define HD   64
#define NH   256

typedef short bf16x8 __attribute__((ext_vector_type(8)));
typedef float f32x4  __attribute__((ext_vector_type(4)));
#define MFMA16(a,b,c) __builtin_amdgcn_mfma_f32_16x16x32_bf16(a,b,c,0,0,0)

// LDS layout (32-bit word offsets)
#define OFF_YF   0        // f32 [16][65]                       = 1040
#define OFF_YP   1040     // u32 planes 3 x [16][33] (h,m,l)    = 1584
#define OFF_TP   2624     // u32 planes 3 x [16][129]           = 6192
#define OFF_PRT  8816     // f32 16 tiles x [16][17]            = 4352
#define OFF_TPS  13168    // 96
#define OFF_W1P  13264    // u32 planes 3 x [256][33]           = 25344
#define SMEM_WORDS 38608
#define SMEM_BYTES (SMEM_WORDS*4)   // 154,432 B (1 block/CU)

__device__ __forceinline__ float rdlane(float v, int i) {
    return __int_as_float(__builtin_amdgcn_readlane(__float_as_int(v), i));
}
__device__ __forceinline__ float wsum64(float v) {
    v += __shfl_xor(v, 1);  v += __shfl_xor(v, 2);  v += __shfl_xor(v, 4);
    v += __shfl_xor(v, 8);  v += __shfl_xor(v, 16); v += __shfl_xor(v, 32);
    return v;
}
__device__ __forceinline__ float tanh_fast(float x) {
    float e = __expf(2.f * x);
    return 1.f - 2.f / (e + 1.f);
}
// exact 3-term bf16 decomposition: x == h + m + l (each bf16-representable)
__device__ __forceinline__ void split3(float x, ushort& h, ushort& m, ushort& l) {
    unsigned xb = __float_as_uint(x);
    float xh = __uint_as_float(xb & 0xffff0000u);
    float xm = x - xh;                       // exact (<=16 mantissa bits)
    unsigned mb = __float_as_uint(xm);
    float xmt = __uint_as_float(mb & 0xffff0000u);
    float xl = xm - xmt;                     // exact (<=8 mantissa bits)
    h = (ushort)(xb >> 16); m = (ushort)(mb >> 16);
    l = (ushort)(__float_as_uint(xl) >> 16);
}

union FU { unsigned u[4]; ushort s[8]; bf16x8 v; };

// 16 waves / block; 4 batch elements (M=16 rows, rows 12-15 pad).
// GEMM1: wave w -> N-tile w (cols 16w..16w+16 of 256), K=64 (y), ie/t via epilogue.
// GEMM2: wave w -> (nt=w&3 of 64 cols, kq=w>>2 of K=256); partials via PRT.
// State y held as C-layout fragments in waves 0..3; published to LDS (f32 + split planes).
__global__ __launch_bounds__(1024)
void node_mfma(const float* __restrict__ x,
               const float* __restrict__ iw1, const float* __restrict__ ib1,
               const float* __restrict__ iw2, const float* __restrict__ ib2,
               const float* __restrict__ ow1, const float* __restrict__ ob1,
               const float* __restrict__ ow2, const float* __restrict__ ob2,
               const float* __restrict__ inter, const float* __restrict__ cons,
               const float* __restrict__ dw1, const float* __restrict__ db1,
               const float* __restrict__ dw2, const float* __restrict__ db2,
               const float* __restrict__ tpts,
               float* __restrict__ out)
{
    extern __shared__ float sm[];
    float*    Yf  = sm + OFF_YF;                  // [16][65]
    unsigned* YP  = (unsigned*)(sm + OFF_YP);     // 3 x [16][33]
    ushort*   YPu = (ushort*)YP;                  // row stride 66, plane stride 1056
    unsigned* TP  = (unsigned*)(sm + OFF_TP);     // 3 x [16][129]
    ushort*   TPu = (ushort*)TP;                  // row stride 258, plane stride 4128
    float*    PRT = sm + OFF_PRT;                 // 16 x [16][17]
    float*    tps = sm + OFF_TPS;
    unsigned* W1P = (unsigned*)(sm + OFF_W1P);    // 3 x [256][33]
    ushort*   W1Pu = (ushort*)W1P;                // row stride 66, plane stride 16896

    const int tid = threadIdx.x;
    const int w   = tid >> 6;       // wave 0..15
    const int ln  = tid & 63;
    const int m   = ln & 15;        // tile row/col index
    const int g4  = ln >> 4;        // quad 0..3
    const int nt  = w & 3;          // GEMM2 N-tile
    const int kq  = w >> 2;         // GEMM2 K-quarter

    // ---- stage W1 (rows 0..63) as split planes into LDS ----
    for (int idx = tid; idx < HD * NH; idx += 1024) {
        int k = idx >> 8, col = idx & 255;
        ushort h, mm, l; split3(ow1[idx], h, mm, l);
        W1Pu[col*66 + k]             = h;
        W1Pu[16896 + col*66 + k]     = mm;
        W1Pu[2*16896 + col*66 + k]   = l;
    }
    if (tid < TPTS) tps[tid] = tpts[tid];

    // ---- persistent per-wave/lane constants ----
    // GEMM2 B-fragments (W2) in registers, 3-term split
    FU b2h[2], b2m[2], b2l[2];
    #pragma unroll
    for (int cc = 0; cc < 2; ++cc)
        #pragma unroll
        for (int j = 0; j < 8; ++j) {
            int k = 64*kq + 32*cc + g4*8 + j;
            ushort h, mm, l; split3(ow2[k*HD + 16*nt + m], h, mm, l);
            b2h[cc].s[j] = h; b2m[cc].s[j] = mm; b2l[cc].s[j] = l;
        }
    const int col1 = 16*w + m;                    // GEMM1 output column
    const float w64c = ow1[64*NH + col1];
    const float w65c = ow1[65*NH + col1];
    const float b1c  = ob1[col1];
    const float b2c  = ob2[16*nt + m];

    // M = conservation @ interaction, scaled by 1/64; per-lane row cp=m%3
    const int cpm = m % 3, base3 = m - cpm;
    float Mr0, Mr1, Mr2;
    {
        float I[9], C[9];
        #pragma unroll
        for (int i = 0; i < 9; ++i) { I[i] = inter[i]; C[i] = cons[i]; }
        float M_[3][3];
        #pragma unroll
        for (int r = 0; r < 3; ++r)
            #pragma unroll
            for (int c = 0; c < 3; ++c)
                M_[r][c] = (C[r*3+0]*I[0*3+c] + C[r*3+1]*I[1*3+c] + C[r*3+2]*I[2*3+c]) * (1.f/64.f);
        Mr0 = (cpm==0) ? M_[0][0] : (cpm==1) ? M_[1][0] : M_[2][0];
        Mr1 = (cpm==0) ? M_[0][1] : (cpm==1) ? M_[1][1] : M_[2][1];
        Mr2 = (cpm==0) ? M_[0][2] : (cpm==1) ? M_[1][2] : M_[2][2];
    }

    // ---- initial state y0 (redundant per element across its 4 waves) ----
    {
        const int el0 = w >> 2;
        const int b0  = blockIdx.x*4 + el0;
        float xs0,xs1,xs2,xs3,xs4,xs5,xs6;
        {
            const float* xp = x + (size_t)b0 * TPTS * NV + ln * NV;
            float v0=xp[0],v1=xp[1],v2=xp[2],v3=xp[3],v4=xp[4],v5=xp[5],v6=xp[6];
            if (ln < 32) {
                const float* xp2 = xp + 64 * NV;
                v0+=xp2[0]; v1+=xp2[1]; v2+=xp2[2]; v3+=xp2[3]; v4+=xp2[4]; v5+=xp2[5]; v6+=xp2[6];
            }
            xs0=wsum64(v0)*(1.f/96.f); xs1=wsum64(v1)*(1.f/96.f); xs2=wsum64(v2)*(1.f/96.f);
            xs3=wsum64(v3)*(1.f/96.f); xs4=wsum64(v4)*(1.f/96.f); xs5=wsum64(v5)*(1.f/96.f);
            xs6=wsum64(v6)*(1.f/96.f);
        }
        float h0v;
        {
            float a = ib1[ln];
            a = fmaf(xs0, iw1[0*HD+ln], a); a = fmaf(xs1, iw1[1*HD+ln], a);
            a = fmaf(xs2, iw1[2*HD+ln], a); a = fmaf(xs3, iw1[3*HD+ln], a);
            a = fmaf(xs4, iw1[4*HD+ln], a); a = fmaf(xs5, iw1[5*HD+ln], a);
            a = fmaf(xs6, iw1[6*HD+ln], a);
            h0v = fmaxf(a, 0.f);
        }
        float y0a = ib2[ln], y0b = ib2[64+ln], y0c = ib2[128+ln];
        #pragma unroll
        for (int k = 0; k < 64; ++k) {
            float hk = rdlane(h0v, k);
            y0a = fmaf(hk, iw2[k*192 + ln],       y0a);
            y0b = fmaf(hk, iw2[k*192 + 64 + ln],  y0b);
            y0c = fmaf(hk, iw2[k*192 + 128 + ln], y0c);
        }
        if ((w & 3) == 0) {
            float yv[3] = {y0a, y0b, y0c};
            #pragma unroll
            for (int r = 0; r < 3; ++r) {
                int row = el0*3 + r;
                Yf[row*65 + ln] = yv[r];
                ushort h, mm, l; split3(yv[r], h, mm, l);
                int ui = row*66 + ln;
                YPu[ui] = h; YPu[1056 + ui] = mm; YPu[2112 + ui] = l;
            }
        }
        if (w == 12) {
            #pragma unroll
            for (int r = 12; r < 16; ++r) {
                Yf[r*65 + ln] = 0.f;
                int ui = r*66 + ln;
                YPu[ui] = 0; YPu[1056 + ui] = 0; YPu[2112 + ui] = 0;
            }
        }
    }
    __syncthreads();

    // state fragments (meaningful in waves 0..3: nt=w, kq=0)
    f32x4 yb, ks;
    if (w < 4) {
        #pragma unroll
        for (int r = 0; r < 4; ++r) yb[r] = Yf[(4*g4 + r)*65 + 16*nt + m];
    }

    // ---- publish state (waves 0..3): f32 + split planes ----
    auto publish = [&](f32x4 ys) {
        #pragma unroll
        for (int r = 0; r < 4; ++r) {
            int row = 4*g4 + r, col = 16*nt + m;
            Yf[row*65 + col] = ys[r];
            ushort h, mm, l; split3(ys[r], h, mm, l);
            int ui = row*66 + col;
            YPu[ui] = h; YPu[1056 + ui] = mm; YPu[2112 + ui] = l;
        }
    };

    // ---- one ODE-func eval (3 barriers: caller supplies the trailing one) ----
    auto evalf = [&](float ts, f32x4& dd) {
        // row sums -> component means -> interaction effect (per-lane for row m)
        float rs = 0.f;
        #pragma unroll
        for (int i = 0; i < 16; ++i) rs += Yf[m*65 + g4*16 + i];
        rs += __shfl_xor(rs, 16); rs += __shfl_xor(rs, 32);   // full row-sum of row m
        float eAll = Mr0*__shfl(rs, base3) + Mr1*__shfl(rs, base3+1) + Mr2*__shfl(rs, base3+2);

        // GEMM1: acc[16x16] over K=64 (y), 3-term split, 6 mfma per 32-chunk
        f32x4 accA = {0,0,0,0}, accB = {0,0,0,0};
        #pragma unroll
        for (int cc = 0; cc < 2; ++cc) {
            FU ah, am, al, bh, bm, bl;
            #pragma unroll
            for (int v = 0; v < 4; ++v) {
                int word = m*33 + cc*16 + g4*4 + v;
                ah.u[v] = YP[word]; am.u[v] = YP[528 + word]; al.u[v] = YP[1056 + word];
                int wb = col1*33 + cc*16 + g4*4 + v;
                bh.u[v] = W1P[wb]; bm.u[v] = W1P[8448 + wb]; bl.u[v] = W1P[16896 + wb];
            }
            accA = MFMA16(ah.v, bh.v, accA);
            accB = MFMA16(ah.v, bm.v, accB);
            accA = MFMA16(am.v, bh.v, accA);
            accB = MFMA16(ah.v, bl.v, accB);
            accA = MFMA16(al.v, bh.v, accA);
            accB = MFMA16(am.v, bm.v, accB);
        }
        // epilogue: + w64*e_row + w65*t + b1, tanh, split, publish to T planes
        #pragma unroll
        for (int r = 0; r < 4; ++r) {
            float er = __shfl(eAll, 4*g4 + r);
            float val = accA[r] + accB[r];
            val = fmaf(w64c, er, val);
            val = fmaf(w65c, ts, val);
            val += b1c;
            float th = tanh_fast(val);
            ushort h, mm, l; split3(th, h, mm, l);
            int ui = (4*g4 + r)*258 + col1;
            TPu[ui] = h; TPu[4128 + ui] = mm; TPu[8256 + ui] = l;
        }
        __syncthreads();   // B1: T planes ready

        // GEMM2 partial: cols 16nt.., K-quarter kq (2 chunks of 32)
        f32x4 pA = {0,0,0,0}, pB = {0,0,0,0};
        #pragma unroll
        for (int cc = 0; cc < 2; ++cc) {
            FU ah, am, al;
            #pragma unroll
            for (int v = 0; v < 4; ++v) {
                int word = m*129 + 32*kq + 16*cc + g4*4 + v;
                ah.u[v] = TP[word]; am.u[v] = TP[2064 + word]; al.u[v] = TP[4128 + word];
            }
            pA = MFMA16(ah.v, b2h[cc].v, pA);
            pB = MFMA16(ah.v, b2m[cc].v, pB);
            pA = MFMA16(am.v, b2h[cc].v, pA);
            pB = MFMA16(ah.v, b2l[cc].v, pB);
            pA = MFMA16(al.v, b2h[cc].v, pA);
            pB = MFMA16(am.v, b2m[cc].v, pB);
        }
        #pragma unroll
        for (int r = 0; r < 4; ++r)
            PRT[w*272 + (4*g4 + r)*17 + m] = pA[r] + pB[r];
        __syncthreads();   // B2: partials ready

        if (w < 4) {
            #pragma unroll
            for (int r = 0; r < 4; ++r) {
                int o = (4*g4 + r)*17 + m;
                dd[r] = b2c + ((PRT[(nt)*272 + o] + PRT[(nt+4)*272 + o])
                             + (PRT[(nt+8)*272 + o] + PRT[(nt+12)*272 + o]));
            }
        }
    };

    // ---- fused decode of committed state (Yf) at time index tix ----
    auto decode = [&](int tix) {
        if (w < 12) {
            const int cc = w % 3, el = w / 3;
            const int b  = blockIdx.x*4 + el;
            float acc = db1[cc*HD + ln];
            #pragma unroll 8
            for (int h = 0; h < 64; ++h)
                acc = fmaf(Yf[w*65 + h], dw1[(cc*HD + h)*HD + ln], acc);
            float hid = fmaxf(acc, 0.f);
            const float* w2p = dw2 + (cc*HD + ln)*NV;
            #pragma unroll
            for (int v = 0; v < NV; ++v) {
                float pv = wsum64(hid * w2p[v]);
                if (ln == 0)
                    out[(((size_t)cc*BTOT + b)*TPTS + tix)*NV + v] = pv + db2[cc*NV + v];
            }
        }
    };

    // ---- RK4 over 95 intervals ----
    decode(0);
    f32x4 dd;
    #pragma unroll 1
    for (int s = 0; s < TPTS - 1; ++s) {
        const float ta = tps[s], tb = tps[s + 1];
        const float dt = tb - ta, hdt = 0.5f * dt;

        evalf(ta, dd);
        if (w < 4) { ks = dd; publish(yb + hdt*dd); }
        __syncthreads();   // B3

        evalf(ta + hdt, dd);
        if (w < 4) { ks += 2.f*dd; publish(yb + hdt*dd); }
        __syncthreads();

        evalf(ta + hdt, dd);
        if (w < 4) { ks += 2.f*dd; publish(yb + dt*dd); }
        __syncthreads();

        evalf(tb, dd);
        if (w < 4) { ks += dd; yb = yb + (dt*(1.f/6.f))*ks; publish(yb); }
        __syncthreads();

        decode(s + 1);
    }
}

extern "C" void kernel_launch(void* const* d_in, const int* in_sizes, int n_in,
                              void* d_out, int out_size, void* d_ws, size_t ws_size,
                              hipStream_t stream) {
    const float* x     = (const float*)d_in[0];
    const float* iw1   = (const float*)d_in[1];
    const float* ib1   = (const float*)d_in[2];
    const float* iw2   = (const float*)d_in[3];
    const float* ib2   = (const float*)d_in[4];
    const float* ow1   = (const float*)d_in[5];
    const float* ob1   = (const float*)d_in[6];
    const float* ow2   = (const float*)d_in[7];
    const float* ob2   = (const float*)d_in[8];
    const float* inter = (const float*)d_in[9];
    const float* cons  = (const float*)d_in[10];
    const float* dw1   = (const float*)d_in[11];
    const float* db1   = (const float*)d_in[12];
    const float* dw2   = (const float*)d_in[13];
    const float* db2   = (const float*)d_in[14];
    const float* tpts  = (const float*)d_in[15];
    float* out = (float*)d_out;

    (void)hipFuncSetAttribute((const void*)node_mfma,
                              hipFuncAttributeMaxDynamicSharedMemorySize,
                              SMEM_BYTES);

    node_mfma<<<BTOT / 4, 1024, SMEM_BYTES, stream>>>(
        x, iw1, ib1, iw2, ib2, ow1, ob1, ow2, ob2,
        inter, cons, dw1, db1, dw2, db2, tpts, out);
}

// Round 6
// 1317.790 us; speedup vs baseline: 3.5920x; 1.6508x over previous
//
#include <hip/hip_runtime.h>

// Problem constants
#define BTOT 1024
#define TPTS 96
#define NV   7
#define HD   64
#define NH   256

typedef short bf16x8 __attribute__((ext_vector_type(8)));
typedef float f32x4  __attribute__((ext_vector_type(4)));
typedef unsigned int u32x4 __attribute__((ext_vector_type(4)));
#define MFMA16(a,b,c) __builtin_amdgcn_mfma_f32_16x16x32_bf16(a,b,c,0,0,0)

// LDS layout (32-bit word offsets), total 10672 words = 42688 B
#define OFF_YP   0        // 2 planes x [16 rows][32 words], XOR-swizzled  = 1024
#define OFF_TP   1024     // 2 planes x [16 rows][128 words], XOR-swizzled = 4096
#define OFF_PRT  5120     // 16 tiles x [16][17] f32                       = 4352
#define OFF_YF   9472     // f32 [16][65] (decode only, commit writes)     = 1040
#define OFF_PS   10512    // f32 [4 slots][16 rows] row-sum partials       = 64
#define OFF_TPS  10576    // 96
#define SMEM_WORDS 10672
#define SMEM_BYTES (SMEM_WORDS*4)

__device__ __forceinline__ float rdlane(float v, int i) {
    return __int_as_float(__builtin_amdgcn_readlane(__float_as_int(v), i));
}
__device__ __forceinline__ float wsum64(float v) {
    v += __shfl_xor(v, 1);  v += __shfl_xor(v, 2);  v += __shfl_xor(v, 4);
    v += __shfl_xor(v, 8);  v += __shfl_xor(v, 16); v += __shfl_xor(v, 32);
    return v;
}
__device__ __forceinline__ float tanh_fast(float x) {
    float e = __expf(2.f * x);
    return 1.f - 2.f / (e + 1.f);
}
__device__ __forceinline__ ushort bf16rn(float x) {
    unsigned u = __float_as_uint(x);
    return (ushort)((u + 0x7fffu + ((u >> 16) & 1u)) >> 16);
}
// 2-term round-to-nearest bf16 decomposition: x ~= h + l, error ~2^-18 rel
__device__ __forceinline__ void split2(float x, ushort& h, ushort& l) {
    h = bf16rn(x);
    float hf = __uint_as_float(((unsigned)h) << 16);
    l = bf16rn(x - hf);
}

union FU { u32x4 uv; unsigned u[4]; ushort s[8]; bf16x8 v; };

// 16 waves/block; 4 batch elements (M=16 rows, rows 12-15 pad); grid = 256 (1 block/CU).
// GEMM1: wave w -> N-tile w (cols 16w..), K=64, W1 frags in REGISTERS.
// GEMM2: wave w -> (nt=w&3, K-quarter kq=w>>2), W2 frags in registers; partials via PRT.
// Activations move through 2 XOR-swizzled bf16 planes (hi/lo); state f32 in waves 0-3 regs.
__global__ __launch_bounds__(1024)
void node_mfma6(const float* __restrict__ x,
                const float* __restrict__ iw1, const float* __restrict__ ib1,
                const float* __restrict__ iw2, const float* __restrict__ ib2,
                const float* __restrict__ ow1, const float* __restrict__ ob1,
                const float* __restrict__ ow2, const float* __restrict__ ob2,
                const float* __restrict__ inter, const float* __restrict__ cons,
                const float* __restrict__ dw1, const float* __restrict__ db1,
                const float* __restrict__ dw2, const float* __restrict__ db2,
                const float* __restrict__ tpts,
                float* __restrict__ out)
{
    extern __shared__ float sm[];
    unsigned* YPw = (unsigned*)(sm + OFF_YP);   // hi plane [16][32]; lo at +512
    unsigned* TPw = (unsigned*)(sm + OFF_TP);   // hi plane [16][128]; lo at +2048
    float*    PRT = sm + OFF_PRT;
    float*    Yf  = sm + OFF_YF;
    float*    PS  = sm + OFF_PS;
    float*    tps = sm + OFF_TPS;

    const int tid = threadIdx.x;
    const int w   = tid >> 6;       // wave 0..15
    const int ln  = tid & 63;
    const int m   = ln & 15;        // tile row/col index
    const int g4  = ln >> 4;        // quad 0..3
    const int nt  = w & 3;          // GEMM2 N-tile (and state-owner id for w<4)
    const int kq  = w >> 2;         // GEMM2 K-quarter

    if (tid < TPTS) tps[tid] = tpts[tid];

    // ---- per-wave constant weight fragments in registers ----
    const int col1 = 16*w + m;                 // GEMM1 output column
    FU w1h[2], w1l[2], w2h[2], w2l[2];
    #pragma unroll
    for (int cc = 0; cc < 2; ++cc) {
        #pragma unroll
        for (int j = 0; j < 8; ++j) {
            ushort h, l;
            int k1 = 32*cc + 8*g4 + j;                       // y index [0,64)
            split2(ow1[k1*NH + col1], h, l);
            w1h[cc].s[j] = h; w1l[cc].s[j] = l;
            int k2 = 64*kq + 32*cc + 8*g4 + j;               // hidden index [0,256)
            split2(ow2[k2*HD + 16*nt + m], h, l);
            w2h[cc].s[j] = h; w2l[cc].s[j] = l;
        }
    }
    const float w64c = ow1[64*NH + col1];
    const float w65c = ow1[65*NH + col1];
    const float b1c  = ob1[col1];
    const float b2c  = ob2[16*nt + m];

    // M = conservation @ interaction, scaled 1/64; per-lane row cpm = m%3
    const int cpm = m % 3, base3 = m - cpm;
    float Mr0, Mr1, Mr2;
    {
        float I[9], C[9];
        #pragma unroll
        for (int i = 0; i < 9; ++i) { I[i] = inter[i]; C[i] = cons[i]; }
        float M_[3][3];
        #pragma unroll
        for (int r = 0; r < 3; ++r)
            #pragma unroll
            for (int c = 0; c < 3; ++c)
                M_[r][c] = (C[r*3+0]*I[0*3+c] + C[r*3+1]*I[1*3+c] + C[r*3+2]*I[2*3+c]) * (1.f/64.f);
        Mr0 = (cpm==0) ? M_[0][0] : (cpm==1) ? M_[1][0] : M_[2][0];
        Mr1 = (cpm==0) ? M_[0][1] : (cpm==1) ? M_[1][1] : M_[2][1];
        Mr2 = (cpm==0) ? M_[0][2] : (cpm==1) ? M_[1][2] : M_[2][2];
    }

    // ---- initial state y0 (each element redundantly by its 4 waves) ----
    {
        const int el0 = w >> 2;
        const int b0  = blockIdx.x*4 + el0;
        float xs0,xs1,xs2,xs3,xs4,xs5,xs6;
        {
            const float* xp = x + (size_t)b0 * TPTS * NV + ln * NV;
            float v0=xp[0],v1=xp[1],v2=xp[2],v3=xp[3],v4=xp[4],v5=xp[5],v6=xp[6];
            if (ln < 32) {
                const float* xp2 = xp + 64 * NV;
                v0+=xp2[0]; v1+=xp2[1]; v2+=xp2[2]; v3+=xp2[3]; v4+=xp2[4]; v5+=xp2[5]; v6+=xp2[6];
            }
            xs0=wsum64(v0)*(1.f/96.f); xs1=wsum64(v1)*(1.f/96.f); xs2=wsum64(v2)*(1.f/96.f);
            xs3=wsum64(v3)*(1.f/96.f); xs4=wsum64(v4)*(1.f/96.f); xs5=wsum64(v5)*(1.f/96.f);
            xs6=wsum64(v6)*(1.f/96.f);
        }
        float h0v;
        {
            float a = ib1[ln];
            a = fmaf(xs0, iw1[0*HD+ln], a); a = fmaf(xs1, iw1[1*HD+ln], a);
            a = fmaf(xs2, iw1[2*HD+ln], a); a = fmaf(xs3, iw1[3*HD+ln], a);
            a = fmaf(xs4, iw1[4*HD+ln], a); a = fmaf(xs5, iw1[5*HD+ln], a);
            a = fmaf(xs6, iw1[6*HD+ln], a);
            h0v = fmaxf(a, 0.f);
        }
        float y0a = ib2[ln], y0b = ib2[64+ln], y0c = ib2[128+ln];
        #pragma unroll
        for (int k = 0; k < 64; ++k) {
            float hk = rdlane(h0v, k);
            y0a = fmaf(hk, iw2[k*192 + ln],       y0a);
            y0b = fmaf(hk, iw2[k*192 + 64 + ln],  y0b);
            y0c = fmaf(hk, iw2[k*192 + 128 + ln], y0c);
        }
        if ((w & 3) == 0) {           // waves 0,4,8,12: publish element el0
            float yv[3] = {y0a, y0b, y0c};
            #pragma unroll
            for (int r = 0; r < 3; ++r) {
                int row = el0*3 + r;
                Yf[row*65 + ln] = yv[r];
                ushort hs, ls; split2(yv[r], hs, ls);
                unsigned hp = hs, lp = ls;
                unsigned hq = __shfl_xor(hp, 1), lq = __shfl_xor(lp, 1);
                if ((ln & 1) == 0) {
                    int wgrp = ln >> 3;
                    int woff = row*32 + ((((unsigned)(wgrp ^ row)) & 7) << 2) + ((ln >> 1) & 3);
                    YPw[woff]       = hp | (hq << 16);
                    YPw[512 + woff] = lp | (lq << 16);
                }
            }
            float S0 = wsum64(y0a), S1 = wsum64(y0b), S2 = wsum64(y0c);
            if (ln < 3) PS[el0*3 + ln] = (ln==0)?S0:(ln==1)?S1:S2;
        }
        if (w == 1 && ln >= 12) PS[ln] = 0.f;            // PS[0][12..15] + slots 1-3
        if (w == 2) {                                     // zero pad rows of Y planes
            YPw[384 + ln] = 0u; YPw[448 + ln] = 0u;
            YPw[896 + ln] = 0u; YPw[960 + ln] = 0u;
        }
        if (w == 12) {                                    // zero pad rows of Yf
            #pragma unroll
            for (int r = 12; r < 16; ++r) Yf[r*65 + ln] = 0.f;
        }
    }
    __syncthreads();

    // state fragments (meaningful in waves 0..3)
    f32x4 yb, ks;
    if (w < 4) {
        #pragma unroll
        for (int r = 0; r < 4; ++r) yb[r] = Yf[(4*g4 + r)*65 + 16*nt + m];
    }

    // ---- publish state planes + PS (waves 0..3); Yf only on commit ----
    auto publish = [&](f32x4 ys, bool commit) {
        #pragma unroll
        for (int r = 0; r < 4; ++r) {
            int row = 4*g4 + r, col = 16*nt + m;
            ushort hs, ls; split2(ys[r], hs, ls);
            unsigned hp = hs, lp = ls;
            unsigned hq = __shfl_xor(hp, 1), lq = __shfl_xor(lp, 1);
            if ((m & 1) == 0) {
                int wgrp = 2*nt + (m >> 3);
                int woff = row*32 + ((((unsigned)(wgrp ^ row)) & 7) << 2) + ((m >> 1) & 3);
                YPw[woff]       = hp | (hq << 16);
                YPw[512 + woff] = lp | (lq << 16);
            }
            if (commit) Yf[row*65 + col] = ys[r];
        }
        float s0 = ys[0], s1 = ys[1], s2 = ys[2], s3 = ys[3];
        #pragma unroll
        for (int d = 1; d < 16; d <<= 1) {
            s0 += __shfl_xor(s0, d); s1 += __shfl_xor(s1, d);
            s2 += __shfl_xor(s2, d); s3 += __shfl_xor(s3, d);
        }
        float sv = (m==0)?s0:(m==1)?s1:(m==2)?s2:s3;
        if (m < 4) PS[nt*16 + 4*g4 + m] = sv;
    };

    // ---- one ODE-func eval (2 internal barriers; caller adds the third) ----
    auto evalf = [&](float ts, f32x4& dd) {
        // interaction effect from row-sum partials
        float rsum = (PS[m] + PS[16+m]) + (PS[32+m] + PS[48+m]);
        float eAll = Mr0*__shfl(rsum, base3) + Mr1*__shfl(rsum, base3+1) + Mr2*__shfl(rsum, base3+2);

        // GEMM1 (K=64): A from Y planes, B from registers
        f32x4 accA = {0,0,0,0}, accB = {0,0,0,0};
        #pragma unroll
        for (int cc = 0; cc < 2; ++cc) {
            FU ah, al;
            int aoff = m*32 + ((((unsigned)((4*cc + g4) ^ m)) & 7) << 2);
            ah.uv = *(const u32x4*)(YPw + aoff);
            al.uv = *(const u32x4*)(YPw + 512 + aoff);
            accA = MFMA16(ah.v, w1h[cc].v, accA);
            accB = MFMA16(ah.v, w1l[cc].v, accB);
            accA = MFMA16(al.v, w1h[cc].v, accA);
        }
        // epilogue: +ie +t +bias, tanh, split, publish T planes (pair-packed b32)
        #pragma unroll
        for (int r = 0; r < 4; ++r) {
            float er = __shfl(eAll, 4*g4 + r);
            float val = accA[r] + accB[r];
            val = fmaf(w64c, er, val);
            val = fmaf(w65c, ts, val);
            val += b1c;
            float th = tanh_fast(val);
            ushort hs, ls; split2(th, hs, ls);
            unsigned hp = hs, lp = ls;
            unsigned hq = __shfl_xor(hp, 1), lq = __shfl_xor(lp, 1);
            if ((m & 1) == 0) {
                int row = 4*g4 + r;
                int wgrp = 2*w + (m >> 3);
                int woff = row*128 + (((wgrp & 24) | ((wgrp ^ row) & 7)) << 2) + ((m >> 1) & 3);
                TPw[woff]        = hp | (hq << 16);
                TPw[2048 + woff] = lp | (lq << 16);
            }
        }
        __syncthreads();   // B1: T planes ready

        // GEMM2 partial (K-quarter kq): A from T planes, B from registers
        f32x4 pA = {0,0,0,0}, pB = {0,0,0,0};
        #pragma unroll
        for (int cc = 0; cc < 2; ++cc) {
            FU ah, al;
            int aoff = m*128 + 32*kq + ((((unsigned)((4*cc + g4) ^ m)) & 7) << 2);
            ah.uv = *(const u32x4*)(TPw + aoff);
            al.uv = *(const u32x4*)(TPw + 2048 + aoff);
            pA = MFMA16(ah.v, w2h[cc].v, pA);
            pB = MFMA16(ah.v, w2l[cc].v, pB);
            pA = MFMA16(al.v, w2h[cc].v, pA);
        }
        #pragma unroll
        for (int r = 0; r < 4; ++r)
            PRT[w*272 + (4*g4 + r)*17 + m] = pA[r] + pB[r];
        __syncthreads();   // B2: partials ready

        if (w < 4) {
            #pragma unroll
            for (int r = 0; r < 4; ++r) {
                int o = (4*g4 + r)*17 + m;
                dd[r] = b2c + ((PRT[nt*272 + o] + PRT[(nt+4)*272 + o])
                             + (PRT[(nt+8)*272 + o] + PRT[(nt+12)*272 + o]));
            }
        }
    };

    // ---- fused decode of committed state (Yf) at time index tix ----
    auto decode = [&](int tix) {
        if (w < 12) {
            const int cc = w % 3, el = w / 3;
            const int b  = blockIdx.x*4 + el;
            float acc = db1[cc*HD + ln];
            #pragma unroll 8
            for (int h = 0; h < 64; ++h)
                acc = fmaf(Yf[w*65 + h], dw1[(cc*HD + h)*HD + ln], acc);
            float hid = fmaxf(acc, 0.f);
            const float* w2p = dw2 + (cc*HD + ln)*NV;
            #pragma unroll
            for (int v = 0; v < NV; ++v) {
                float pv = wsum64(hid * w2p[v]);
                if (ln == 0)
                    out[(((size_t)cc*BTOT + b)*TPTS + tix)*NV + v] = pv + db2[cc*NV + v];
            }
        }
    };

    // ---- RK4 over 95 intervals ----
    decode(0);
    f32x4 dd;
    #pragma unroll 1
    for (int s = 0; s < TPTS - 1; ++s) {
        const float ta = tps[s], tb = tps[s + 1];
        const float dt = tb - ta, hdt = 0.5f * dt;

        evalf(ta, dd);
        if (w < 4) { ks = dd; publish(yb + hdt*dd, false); }
        __syncthreads();   // B3: Y planes / PS ready

        evalf(ta + hdt, dd);
        if (w < 4) { ks += 2.f*dd; publish(yb + hdt*dd, false); }
        __syncthreads();

        evalf(ta + hdt, dd);
        if (w < 4) { ks += 2.f*dd; publish(yb + dt*dd, false); }
        __syncthreads();

        evalf(tb, dd);
        if (w < 4) { ks += dd; yb = yb + (dt*(1.f/6.f))*ks; publish(yb, true); }
        __syncthreads();

        decode(s + 1);
    }
}

extern "C" void kernel_launch(void* const* d_in, const int* in_sizes, int n_in,
                              void* d_out, int out_size, void* d_ws, size_t ws_size,
                              hipStream_t stream) {
    const float* x     = (const float*)d_in[0];
    const float* iw1   = (const float*)d_in[1];
    const float* ib1   = (const float*)d_in[2];
    const float* iw2   = (const float*)d_in[3];
    const float* ib2   = (const float*)d_in[4];
    const float* ow1   = (const float*)d_in[5];
    const float* ob1   = (const float*)d_in[6];
    const float* ow2   = (const float*)d_in[7];
    const float* ob2   = (const float*)d_in[8];
    const float* inter = (const float*)d_in[9];
    const float* cons  = (const float*)d_in[10];
    const float* dw1   = (const float*)d_in[11];
    const float* db1   = (const float*)d_in[12];
    const float* dw2   = (const float*)d_in[13];
    const float* db2   = (const float*)d_in[14];
    const float* tpts  = (const float*)d_in[15];
    float* out = (float*)d_out;

    node_mfma6<<<BTOT / 4, 1024, SMEM_BYTES, stream>>>(
        x, iw1, ib1, iw2, ib2, ow1, ob1, ow2, ob2,
        inter, cons, dw1, db1, dw2, db2, tpts, out);
}

// Round 7
// 1167.052 us; speedup vs baseline: 4.0559x; 1.1292x over previous
//
#include <hip/hip_runtime.h>

// Problem constants
#define BTOT 1024
#define TPTS 96
#define NV   7
#define HD   64
#define NH   256

typedef short bf16x8 __attribute__((ext_vector_type(8)));
typedef float f32x4  __attribute__((ext_vector_type(4)));
typedef unsigned int u32x4 __attribute__((ext_vector_type(4)));
#define MFMA16(a,b,c) __builtin_amdgcn_mfma_f32_16x16x32_bf16(a,b,c,0,0,0)

// LDS layout (32-bit word offsets), total 25296 words = 101184 B (1 block/CU)
#define OFF_YP   0        // 2 planes x [16 rows][32 words], XOR-swizzled   = 1024
#define OFF_TP   1024     // 2 planes x [16 rows][128 words], XOR-swizzled  = 4096
#define OFF_PRT  5120     // 16 waves x [16 m][20 rows-padded] f32          = 5120
#define OFF_YF   10240    // f32 [16][65] (decode only, commit writes)      = 1040
#define OFF_PS   11280    // f32 [4 nt][16 rows] row-sum partials           = 64
#define OFF_TPS  11344    // 96
#define OFF_DW1  11440    // f32 [3][64][64] decode layer-1 weights         = 12288
#define OFF_DW2  23728    // f32 [3][64][7]                                 = 1344
#define OFF_DB1  25072    // 192
#define OFF_DB2  25264    // 32 (21 used)
#define SMEM_WORDS 25296
#define SMEM_BYTES (SMEM_WORDS*4)

__device__ __forceinline__ float rdlane(float v, int i) {
    return __int_as_float(__builtin_amdgcn_readlane(__float_as_int(v), i));
}
__device__ __forceinline__ float wsum64(float v) {
    v += __shfl_xor(v, 1);  v += __shfl_xor(v, 2);  v += __shfl_xor(v, 4);
    v += __shfl_xor(v, 8);  v += __shfl_xor(v, 16); v += __shfl_xor(v, 32);
    return v;
}
__device__ __forceinline__ float tanh_fast(float x) {
    float e = __expf(2.f * x);
    return 1.f - 2.f / (e + 1.f);
}
__device__ __forceinline__ ushort bf16rn(float x) {
    unsigned u = __float_as_uint(x);
    return (ushort)((u + 0x7fffu + ((u >> 16) & 1u)) >> 16);
}
// 2-term round-to-nearest bf16 decomposition: x ~= h + l, error ~2^-18 rel
__device__ __forceinline__ void split2(float x, ushort& h, ushort& l) {
    h = bf16rn(x);
    float hf = __uint_as_float(((unsigned)h) << 16);
    l = bf16rn(x - hf);
}

union FU { u32x4 uv; unsigned u[4]; ushort s[8]; bf16x8 v; };

// 16 waves/block; 4 batch elements (M=16 rows, rows 12-15 pad); grid = 256 (1 block/CU).
// GEMM1: wave w -> N-tile w (cols 16w..), K=64, W1 frags in registers.
// GEMM2: wave w -> (nt=w&3, K-quarter kq=w>>2), W2 frags in registers; partials via PRT b128.
// State replicated across ALL waves; publish sliced by kq (1 row per thread).
__global__ __launch_bounds__(1024)
void node_mfma7(const float* __restrict__ x,
                const float* __restrict__ iw1, const float* __restrict__ ib1,
                const float* __restrict__ iw2, const float* __restrict__ ib2,
                const float* __restrict__ ow1, const float* __restrict__ ob1,
                const float* __restrict__ ow2, const float* __restrict__ ob2,
                const float* __restrict__ inter, const float* __restrict__ cons,
                const float* __restrict__ dw1, const float* __restrict__ db1,
                const float* __restrict__ dw2, const float* __restrict__ db2,
                const float* __restrict__ tpts,
                float* __restrict__ out)
{
    extern __shared__ float sm[];
    unsigned* YPw = (unsigned*)(sm + OFF_YP);   // hi plane [16][32]; lo at +512
    unsigned* TPw = (unsigned*)(sm + OFF_TP);   // hi plane [16][128]; lo at +2048
    float*    PRT = sm + OFF_PRT;
    float*    Yf  = sm + OFF_YF;
    float*    PS  = sm + OFF_PS;
    float*    tps = sm + OFF_TPS;
    float*    DW1 = sm + OFF_DW1;
    float*    DW2 = sm + OFF_DW2;
    float*    DB1 = sm + OFF_DB1;
    float*    DB2 = sm + OFF_DB2;

    const int tid = threadIdx.x;
    const int w   = tid >> 6;       // wave 0..15
    const int ln  = tid & 63;
    const int m   = ln & 15;        // tile row/col index
    const int g4  = ln >> 4;        // quad 0..3
    const int nt  = w & 3;          // GEMM2 N-tile / state tile
    const int kq  = w >> 2;         // GEMM2 K-quarter / publish row-slice

    // ---- stage decode weights + t into LDS ----
    for (int idx = tid; idx < 3*HD*HD; idx += 1024) DW1[idx] = dw1[idx];
    if (tid < 3*HD)  { for (int v = 0; v < NV; ++v) DW2[tid*NV + v] = dw2[tid*NV + v]; }
    if (tid < 192)   DB1[tid] = db1[tid];
    if (tid < 21)    DB2[tid] = db2[tid];
    if (tid < TPTS)  tps[tid] = tpts[tid];

    // ---- per-wave constant weight fragments in registers ----
    const int col1 = 16*w + m;                 // GEMM1 output column
    FU w1h[2], w1l[2], w2h[2], w2l[2];
    #pragma unroll
    for (int cc = 0; cc < 2; ++cc) {
        #pragma unroll
        for (int j = 0; j < 8; ++j) {
            ushort h, l;
            int k1 = 32*cc + 8*g4 + j;                       // y index [0,64)
            split2(ow1[k1*NH + col1], h, l);
            w1h[cc].s[j] = h; w1l[cc].s[j] = l;
            int k2 = 64*kq + 32*cc + 8*g4 + j;               // hidden index [0,256)
            split2(ow2[k2*HD + 16*nt + m], h, l);
            w2h[cc].s[j] = h; w2l[cc].s[j] = l;
        }
    }
    const float w64c = ow1[64*NH + col1];
    const float w65c = ow1[65*NH + col1];
    const float b1c  = ob1[col1];
    const float b2c  = ob2[16*nt + m];

    // M = conservation @ interaction, scaled 1/64; per-lane row cpm = m%3
    const int cpm = m % 3, base3 = m - cpm;
    float Mr0, Mr1, Mr2;
    {
        float I[9], C[9];
        #pragma unroll
        for (int i = 0; i < 9; ++i) { I[i] = inter[i]; C[i] = cons[i]; }
        float M_[3][3];
        #pragma unroll
        for (int r = 0; r < 3; ++r)
            #pragma unroll
            for (int c = 0; c < 3; ++c)
                M_[r][c] = (C[r*3+0]*I[0*3+c] + C[r*3+1]*I[1*3+c] + C[r*3+2]*I[2*3+c]) * (1.f/64.f);
        Mr0 = (cpm==0) ? M_[0][0] : (cpm==1) ? M_[1][0] : M_[2][0];
        Mr1 = (cpm==0) ? M_[0][1] : (cpm==1) ? M_[1][1] : M_[2][1];
        Mr2 = (cpm==0) ? M_[0][2] : (cpm==1) ? M_[1][2] : M_[2][2];
    }

    // ---- initial state y0 (each element redundantly by its 4 waves) ----
    {
        const int el0 = w >> 2;
        const int b0  = blockIdx.x*4 + el0;
        float xs0,xs1,xs2,xs3,xs4,xs5,xs6;
        {
            const float* xp = x + (size_t)b0 * TPTS * NV + ln * NV;
            float v0=xp[0],v1=xp[1],v2=xp[2],v3=xp[3],v4=xp[4],v5=xp[5],v6=xp[6];
            if (ln < 32) {
                const float* xp2 = xp + 64 * NV;
                v0+=xp2[0]; v1+=xp2[1]; v2+=xp2[2]; v3+=xp2[3]; v4+=xp2[4]; v5+=xp2[5]; v6+=xp2[6];
            }
            xs0=wsum64(v0)*(1.f/96.f); xs1=wsum64(v1)*(1.f/96.f); xs2=wsum64(v2)*(1.f/96.f);
            xs3=wsum64(v3)*(1.f/96.f); xs4=wsum64(v4)*(1.f/96.f); xs5=wsum64(v5)*(1.f/96.f);
            xs6=wsum64(v6)*(1.f/96.f);
        }
        float h0v;
        {
            float a = ib1[ln];
            a = fmaf(xs0, iw1[0*HD+ln], a); a = fmaf(xs1, iw1[1*HD+ln], a);
            a = fmaf(xs2, iw1[2*HD+ln], a); a = fmaf(xs3, iw1[3*HD+ln], a);
            a = fmaf(xs4, iw1[4*HD+ln], a); a = fmaf(xs5, iw1[5*HD+ln], a);
            a = fmaf(xs6, iw1[6*HD+ln], a);
            h0v = fmaxf(a, 0.f);
        }
        float y0a = ib2[ln], y0b = ib2[64+ln], y0c = ib2[128+ln];
        #pragma unroll
        for (int k = 0; k < 64; ++k) {
            float hk = rdlane(h0v, k);
            y0a = fmaf(hk, iw2[k*192 + ln],       y0a);
            y0b = fmaf(hk, iw2[k*192 + 64 + ln],  y0b);
            y0c = fmaf(hk, iw2[k*192 + 128 + ln], y0c);
        }
        if ((w & 3) == 0) {           // waves 0,4,8,12: publish element el0
            float yv[3] = {y0a, y0b, y0c};
            #pragma unroll
            for (int r = 0; r < 3; ++r) {
                int row = el0*3 + r;
                Yf[row*65 + ln] = yv[r];
                ushort hs, ls; split2(yv[r], hs, ls);
                unsigned hp = hs, lp = ls;
                unsigned hq = __shfl_xor(hp, 1), lq = __shfl_xor(lp, 1);
                if ((ln & 1) == 0) {
                    int wgrp = ln >> 3;
                    int woff = row*32 + ((((unsigned)(wgrp ^ row)) & 7) << 2) + ((ln >> 1) & 3);
                    YPw[woff]       = hp | (hq << 16);
                    YPw[512 + woff] = lp | (lq << 16);
                }
            }
            float S0 = wsum64(y0a), S1 = wsum64(y0b), S2 = wsum64(y0c);
            if (ln < 3) PS[el0*3 + ln] = (ln==0)?S0:(ln==1)?S1:S2;
        }
        if (w == 1 && ln >= 12) PS[ln] = 0.f;            // PS[0][12..15] + slots 1-3
        if (w == 2) {                                     // zero pad rows of Y planes
            YPw[384 + ln] = 0u; YPw[448 + ln] = 0u;
            YPw[896 + ln] = 0u; YPw[960 + ln] = 0u;
        }
        if (w == 12) {                                    // zero pad rows of Yf
            #pragma unroll
            for (int r = 12; r < 16; ++r) Yf[r*65 + ln] = 0.f;
        }
    }
    __syncthreads();

    // state fragments, replicated in ALL waves (bitwise-identical within an nt-group)
    f32x4 yb, ks;
    #pragma unroll
    for (int r = 0; r < 4; ++r) yb[r] = Yf[(4*g4 + r)*65 + 16*nt + m];

    // ---- publish (all waves): slice row r=kq of this wave's fragment ----
    auto publish = [&](f32x4 ys, bool commit) {
        float yv = (kq==0)?ys[0]:(kq==1)?ys[1]:(kq==2)?ys[2]:ys[3];
        const int row = 4*g4 + kq;
        ushort hs, ls; split2(yv, hs, ls);
        unsigned hp = hs, lp = ls;
        unsigned hq = __shfl_xor(hp, 1), lq = __shfl_xor(lp, 1);
        if ((m & 1) == 0) {
            int wgrp = 2*nt + (m >> 3);
            int woff = row*32 + ((((unsigned)(wgrp ^ row)) & 7) << 2) + ((m >> 1) & 3);
            YPw[woff]       = hp | (hq << 16);
            YPw[512 + woff] = lp | (lq << 16);
        }
        if (commit) Yf[row*65 + 16*nt + m] = yv;
        // row-sum partial over this wave's 16 columns
        float s = yv;
        s += __shfl_xor(s, 1); s += __shfl_xor(s, 2);
        s += __shfl_xor(s, 4); s += __shfl_xor(s, 8);
        if (m == 0) PS[nt*16 + row] = s;
    };

    // ---- one ODE-func eval (2 internal barriers; caller adds the third) ----
    auto evalf = [&](float ts, f32x4& dd) {
        // interaction effect from row-sum partials
        float rsum = (PS[m] + PS[16+m]) + (PS[32+m] + PS[48+m]);
        float eAll = Mr0*__shfl(rsum, base3) + Mr1*__shfl(rsum, base3+1) + Mr2*__shfl(rsum, base3+2);

        // GEMM1 (K=64): A from Y planes, B from registers
        f32x4 accA = {0,0,0,0}, accB = {0,0,0,0};
        #pragma unroll
        for (int cc = 0; cc < 2; ++cc) {
            FU ah, al;
            int aoff = m*32 + ((((unsigned)((4*cc + g4) ^ m)) & 7) << 2);
            ah.uv = *(const u32x4*)(YPw + aoff);
            al.uv = *(const u32x4*)(YPw + 512 + aoff);
            accA = MFMA16(ah.v, w1h[cc].v, accA);
            accB = MFMA16(ah.v, w1l[cc].v, accB);
            accA = MFMA16(al.v, w1h[cc].v, accA);
        }
        // epilogue: +ie +t +bias, tanh, split, publish T planes (pair-packed b32)
        #pragma unroll
        for (int r = 0; r < 4; ++r) {
            float er = __shfl(eAll, 4*g4 + r);
            float val = accA[r] + accB[r];
            val = fmaf(w64c, er, val);
            val = fmaf(w65c, ts, val);
            val += b1c;
            float th = tanh_fast(val);
            ushort hs, ls; split2(th, hs, ls);
            unsigned hp = hs, lp = ls;
            unsigned hq = __shfl_xor(hp, 1), lq = __shfl_xor(lp, 1);
            if ((m & 1) == 0) {
                int row = 4*g4 + r;
                int wgrp = 2*w + (m >> 3);
                int woff = row*128 + (((wgrp & 24) | ((wgrp ^ row) & 7)) << 2) + ((m >> 1) & 3);
                TPw[woff]        = hp | (hq << 16);
                TPw[2048 + woff] = lp | (lq << 16);
            }
        }
        __syncthreads();   // B1: T planes ready

        // GEMM2 partial (K-quarter kq): A from T planes, B from registers
        f32x4 pA = {0,0,0,0}, pB = {0,0,0,0};
        #pragma unroll
        for (int cc = 0; cc < 2; ++cc) {
            FU ah, al;
            int aoff = m*128 + 32*kq + ((((unsigned)((4*cc + g4) ^ m)) & 7) << 2);
            ah.uv = *(const u32x4*)(TPw + aoff);
            al.uv = *(const u32x4*)(TPw + 2048 + aoff);
            pA = MFMA16(ah.v, w2h[cc].v, pA);
            pB = MFMA16(ah.v, w2l[cc].v, pB);
            pA = MFMA16(al.v, w2h[cc].v, pA);
        }
        // b128 partial write: PRT[w][m][rows 4g4..4g4+3] (stride 20, aligned, conflict-lite)
        f32x4 pr = pA + pB;
        *(f32x4*)(PRT + w*320 + m*20 + 4*g4) = pr;
        __syncthreads();   // B2: partials ready

        // all waves reduce for their nt (4 x b128 reads)
        const float* pb = PRT + m*20 + 4*g4;
        f32x4 q0 = *(const f32x4*)(pb + nt*320);
        f32x4 q1 = *(const f32x4*)(pb + (nt+4)*320);
        f32x4 q2 = *(const f32x4*)(pb + (nt+8)*320);
        f32x4 q3 = *(const f32x4*)(pb + (nt+12)*320);
        f32x4 qq = (q0 + q1) + (q2 + q3);
        dd[0] = qq[0] + b2c; dd[1] = qq[1] + b2c;
        dd[2] = qq[2] + b2c; dd[3] = qq[3] + b2c;
    };

    // ---- fused decode of committed state (Yf) at time index tix (LDS weights) ----
    auto decode = [&](int tix) {
        if (w < 12) {
            const int cc = w % 3, el = w / 3;
            const int b  = blockIdx.x*4 + el;
            float acc = DB1[cc*HD + ln];
            #pragma unroll 8
            for (int h = 0; h < 64; ++h)
                acc = fmaf(Yf[w*65 + h], DW1[(cc*HD + h)*HD + ln], acc);
            float hid = fmaxf(acc, 0.f);
            #pragma unroll
            for (int v = 0; v < NV; ++v) {
                float pv = wsum64(hid * DW2[(cc*HD + ln)*NV + v]);
                if (ln == 0)
                    out[(((size_t)cc*BTOT + b)*TPTS + tix)*NV + v] = pv + DB2[cc*NV + v];
            }
        }
    };

    // ---- RK4 over 95 intervals ----
    decode(0);
    f32x4 dd;
    #pragma unroll 1
    for (int s = 0; s < TPTS - 1; ++s) {
        const float ta = tps[s], tb = tps[s + 1];
        const float dt = tb - ta, hdt = 0.5f * dt;

        evalf(ta, dd);
        ks = dd; publish(yb + hdt*dd, false);
        __syncthreads();   // B3: Y planes / PS ready

        evalf(ta + hdt, dd);
        ks += 2.f*dd; publish(yb + hdt*dd, false);
        __syncthreads();

        evalf(ta + hdt, dd);
        ks += 2.f*dd; publish(yb + dt*dd, false);
        __syncthreads();

        evalf(tb, dd);
        ks += dd; yb = yb + (dt*(1.f/6.f))*ks; publish(yb, true);
        __syncthreads();

        decode(s + 1);
    }
}

extern "C" void kernel_launch(void* const* d_in, const int* in_sizes, int n_in,
                              void* d_out, int out_size, void* d_ws, size_t ws_size,
                              hipStream_t stream) {
    const float* x     = (const float*)d_in[0];
    const float* iw1   = (const float*)d_in[1];
    const float* ib1   = (const float*)d_in[2];
    const float* iw2   = (const float*)d_in[3];
    const float* ib2   = (const float*)d_in[4];
    const float* ow1   = (const float*)d_in[5];
    const float* ob1   = (const float*)d_in[6];
    const float* ow2   = (const float*)d_in[7];
    const float* ob2   = (const float*)d_in[8];
    const float* inter = (const float*)d_in[9];
    const float* cons  = (const float*)d_in[10];
    const float* dw1   = (const float*)d_in[11];
    const float* db1   = (const float*)d_in[12];
    const float* dw2   = (const float*)d_in[13];
    const float* db2   = (const float*)d_in[14];
    const float* tpts  = (const float*)d_in[15];
    float* out = (float*)d_out;

    // dynamic LDS > 64 KB requires the attribute (host-side, graph-capture safe)
    (void)hipFuncSetAttribute((const void*)node_mfma7,
                              hipFuncAttributeMaxDynamicSharedMemorySize,
                              SMEM_BYTES);

    node_mfma7<<<BTOT / 4, 1024, SMEM_BYTES, stream>>>(
        x, iw1, ib1, iw2, ib2, ow1, ob1, ow2, ob2,
        inter, cons, dw1, db1, dw2, db2, tpts, out);
}